// Round 16
// baseline (13.605 us; speedup 1.0000x reference)
//
#include <hip/hip_runtime.h>
#include <hip/hip_bf16.h>

#define NB 2048

typedef __attribute__((ext_vector_type(8))) short bf16x8;
typedef __attribute__((ext_vector_type(4))) float f32x4;

__device__ __forceinline__ float qget(const float4& q, int c) {
    return c == 0 ? q.x : c == 1 ? q.y : c == 2 ? q.z : q.w;
}

// DPP move (bound_ctrl=1). VALU pipe — no LDS.
template<int CTRL>
__device__ __forceinline__ float dpp_mov(float x) {
    union { float f; int i; } u; u.f = x;
    u.i = __builtin_amdgcn_mov_dpp(u.i, CTRL, 0xf, 0xf, true);
    return u.f;
}
// sum over each row-of-16; result lands in lane 15 of each row
#define ROWSUM16(x) { x += dpp_mov<0x111>(x); x += dpp_mov<0x112>(x); \
                      x += dpp_mov<0x114>(x); x += dpp_mov<0x118>(x); }

// One Gauss-Jordan step (K literal). pv: readlane; f: DPP quad bcast; q: bpermute.
#define GJ_STEP(K) { \
    constexpr int kq = (K) >> 2, kc = (K) & 3; \
    float akc = (kc == 0) ? a0 : (kc == 1) ? a1 : (kc == 2) ? a2 : a3; \
    union { float f; int i; } ua_, uf_, up_; \
    ua_.f = akc; \
    up_.i = __builtin_amdgcn_readlane(ua_.i, ((K) << 2) | kq); \
    uf_.i = __builtin_amdgcn_mov_dpp(ua_.i, kq * 0x55, 0xf, 0xf, 0); \
    float pv = up_.f; \
    float f  = uf_.f; \
    float q0 = __shfl(a0, ((K) << 2) | gq2); \
    float q1 = __shfl(a1, ((K) << 2) | gq2); \
    float q2 = __shfl(a2, ((K) << 2) | gq2); \
    float q3 = __shfl(a3, ((K) << 2) | gq2); \
    float pinv = 1.0f / pv; \
    bool piv = (gi == (K)); \
    float r0 = q0 * pinv, r1 = q1 * pinv, r2 = q2 * pinv, r3 = q3 * pinv; \
    a0 = piv ? r0 : fmaf(-f, r0, a0); \
    a1 = piv ? r1 : fmaf(-f, r1, a1); \
    a2 = piv ? r2 : fmaf(-f, r2, a2); \
    a3 = piv ? r3 : fmaf(-f, r3, a3); \
    float colv = piv ? pinv : -f * pinv; \
    bool fix = (gq2 == kq); \
    if      (kc == 0) a0 = fix ? colv : a0; \
    else if (kc == 1) a1 = fix ? colv : a1; \
    else if (kc == 2) a2 = fix ? colv : a2; \
    else              a3 = fix ? colv : a3; \
}

// One block per batch (2048 blocks, 256 thr, occupancy 6).
// Thread t owns cur row (ku,iu)=G[b,ku,iu,:].
// scalar[b] = <Aprev-Acur,Minv> - sum_i dT[i]*R[i] + sum_m T[m]*Q[m] - <term4,Minv>
// term4 = 16x16x256 bf16 MFMA from single staged XA (B via u16 gather — proven).
// Prev tile issued right after barA: latency hides under MFMA + qd dots.
__global__ __launch_bounds__(256, 6)
void curvature_kernel(const float* __restrict__ metric,
                      const float* __restrict__ gamma,
                      float* __restrict__ out)
{
    const int bid = blockIdx.x;
    const int b = ((bid & 7) << 8) | (bid >> 3);   // XCD swizzle: b, b-1 share an L2
    const int t = threadIdx.x;
    const int wv = t >> 6, lane = t & 63;
    const int ku = t >> 4, iu = t & 15;
    const int r16 = lane & 15, hi = lane >> 4;     // r16 == iu, hi == ku&3
    const int gjw = b & 3;                          // GJ wave id: spread across SIMDs

    __shared__ alignas(16) unsigned short XA[16][264];  // XA[b][a*16+c] = G[a,b,c]
    __shared__ alignas(16) float MINV[16][20];
    __shared__ alignas(16) float TT[16][20];             // TT[m][k] = G[k,m,k]
    __shared__ float red[4];

    const float* Gc = gamma + ((size_t)b << 12);
    const float* Gp = gamma + ((size_t)((b + NB - 1) & (NB - 1)) << 12);
    const float4* gc4 = (const float4*)(Gc + (t << 4));
    const float4* gp4 = (const float4*)(Gp + (t << 4));
    const bool isGJ = (wv == gjw);

    // ---- cur-tile loads (16 regs) + diag scalar (L1 hit) + metric (GJ) ----
    float4 g0 = gc4[0], g1 = gc4[1], g2 = gc4[2], g3 = gc4[3];
    float gku = Gc[(t << 4) + ku];                 // G[b, ku, iu, ku]
    float4 mrow = {0.f, 0.f, 0.f, 0.f};
    if (isGJ) mrow = ((const float4*)(metric + ((size_t)b << 8)))[lane];

    // ---- GJ wave: Gauss-Jordan inverse (SPD, no pivoting), BEFORE barA ----
    if (isGJ) {
        const int gi = lane >> 2, gq2 = lane & 3;
        float a0 = mrow.x, a1 = mrow.y, a2 = mrow.z, a3 = mrow.w;
        GJ_STEP(0)  GJ_STEP(1)  GJ_STEP(2)  GJ_STEP(3)
        GJ_STEP(4)  GJ_STEP(5)  GJ_STEP(6)  GJ_STEP(7)
        GJ_STEP(8)  GJ_STEP(9)  GJ_STEP(10) GJ_STEP(11)
        GJ_STEP(12) GJ_STEP(13) GJ_STEP(14) GJ_STEP(15)
        MINV[gi][4*gq2 + 0] = a0;
        MINV[gi][4*gq2 + 1] = a1;
        MINV[gi][4*gq2 + 2] = a2;
        MINV[gi][4*gq2 + 3] = a3;
    }

    // ---- pack cur to bf16, stage XA (contiguous b128) ----
    {
        float4 gq[4] = {g0, g1, g2, g3};
        unsigned yp[8];
        #pragma unroll
        for (int q = 0; q < 8; ++q) {
            union { __hip_bfloat162 h; unsigned u; } cv;
            cv.h = __float22bfloat162_rn(
                make_float2(qget(gq[q >> 1], (q & 1) * 2),
                            qget(gq[q >> 1], (q & 1) * 2 + 1)));
            yp[q] = cv.u;
        }
        uint4* xd = (uint4*)&XA[iu][ku << 4];
        xd[0] = make_uint4(yp[0], yp[1], yp[2], yp[3]);
        xd[1] = make_uint4(yp[4], yp[5], yp[6], yp[7]);
    }
    TT[iu][ku] = gku;
    __syncthreads();   // barA: XA, TT, MINV visible

    // ---- issue prev loads NOW: latency hides under MFMA + qd dots ----
    float4 v0 = gp4[0], v1 = gp4[1], v2 = gp4[2], v3 = gp4[3];
    float pku = Gp[(t << 4) + ku];                 // G[b-1, ku, iu, ku]

    // ---- Minv row (broadcast b128 reads) ----
    float4 m0, m1, m2, m3;
    {
        const float4* mv = (const float4*)&MINV[iu][0];
        m0 = mv[0]; m1 = mv[1]; m2 = mv[2]; m3 = mv[3];
    }

    // ---- every wave: 2 K-steps of the 16x16x256 MFMA ----
    // A-frag: contiguous b128. B-frag: u16 gather (proven slot-consistent l).
    f32x4 acc = {0.f, 0.f, 0.f, 0.f};
    #pragma unroll
    for (int s = 0; s < 2; ++s) {
        const int S = 2 * wv + s;
        bf16x8 av = *(const bf16x8*)&XA[r16][(S << 5) + (hi << 3)];
        const int brow = 2 * S + (hi >> 1);
        const int cbase = ((hi & 1) << 7) + r16;
        bf16x8 bv;
        #pragma unroll
        for (int e = 0; e < 8; ++e)
            bv[e] = (short)XA[brow][cbase + (e << 4)];
        acc = __builtin_amdgcn_mfma_f32_16x16x32_bf16(av, bv, acc, 0, 0, 0);
    }

    // ---- qd = <cur,mr>, R = sum mr (static unroll, quad-select) ----
    float qd = 0.f, R = 0.f;
    {
        float4 gq[4] = {g0, g1, g2, g3};
        #pragma unroll
        for (int k = 0; k < 16; ++k) {
            float m = qget((k < 4) ? m0 : (k < 8) ? m1 : (k < 12) ? m2 : m3, k & 3);
            qd = fmaf(qget(gq[k >> 2], k & 3), m, qd);
            R += m;
        }
    }

    // ---- pd = <prev,mr> (prev arrived under the compute above) ----
    float pd = 0.f;
    {
        float4 vq[4] = {v0, v1, v2, v3};
        #pragma unroll
        for (int k = 0; k < 16; ++k) {
            float m = qget((k < 4) ? m0 : (k < 8) ? m1 : (k < 12) ? m2 : m3, k & 3);
            pd = fmaf(qget(vq[k >> 2], k & 3), m, pd);
        }
    }

    // ---- group-16 DPP sums: tsum = T[ku], qsum = sum qd (land at iu==15) ----
    float tsum = TT[ku][iu];       // transpose exchange (1 b32, conflict-free)
    float qsum = qd;
    ROWSUM16(tsum)
    ROWSUM16(qsum)

    float dt = pku - gku;
    // t4c via Minv symmetry: MINV[4hi+q][r16] == mr[4hi+q]  (r16==iu)
    float4 mq = (hi == 0) ? m0 : (hi == 1) ? m1 : (hi == 2) ? m2 : m3;
    float t4c = acc[0] * mq.x + acc[1] * mq.y + acc[2] * mq.z + acc[3] * mq.w;

    float s = pd - dt * R - t4c;
    if (iu == 15) s = fmaf(tsum - 1.0f, qsum, s);  // group term once per 16-group

    // ---- wave sum via DPP (total lands in lane 63) ----
    ROWSUM16(s)
    s += dpp_mov<0x142>(s);   // row_bcast15
    s += dpp_mov<0x143>(s);   // row_bcast31
    if (lane == 63) red[wv] = s;
    __syncthreads();
    if (t == 0) out[b] = (red[0] + red[1]) + (red[2] + red[3]);
}

extern "C" void kernel_launch(void* const* d_in, const int* in_sizes, int n_in,
                              void* d_out, int out_size, void* d_ws, size_t ws_size,
                              hipStream_t stream) {
    const float* metric = (const float*)d_in[0];   // (2048, 16, 16) f32
    const float* gamma  = (const float*)d_in[1];   // (2048, 16, 16, 16) f32
    float* out = (float*)d_out;                    // (2048,) f32
    curvature_kernel<<<NB, 256, 0, stream>>>(metric, gamma, out);
}

// Round 17
// 12.457 us; speedup vs baseline: 1.0921x; 1.0921x over previous
//
#include <hip/hip_runtime.h>
#include <hip/hip_bf16.h>

#define NB 2048

typedef __attribute__((ext_vector_type(8))) short bf16x8;
typedef __attribute__((ext_vector_type(4))) float f32x4;

__device__ __forceinline__ float qget(const float4& q, int c) {
    return c == 0 ? q.x : c == 1 ? q.y : c == 2 ? q.z : q.w;
}

// DPP move (bound_ctrl=1). VALU pipe — no LDS.
template<int CTRL>
__device__ __forceinline__ float dpp_mov(float x) {
    union { float f; int i; } u; u.f = x;
    u.i = __builtin_amdgcn_mov_dpp(u.i, CTRL, 0xf, 0xf, true);
    return u.f;
}
// sum over each row-of-16; result lands in lane 15 of each row
#define ROWSUM16(x) { x += dpp_mov<0x111>(x); x += dpp_mov<0x112>(x); \
                      x += dpp_mov<0x114>(x); x += dpp_mov<0x118>(x); }

// One Gauss-Jordan step (K literal). pv: readlane; f: DPP quad bcast; q: bpermute.
#define GJ_STEP(K) { \
    constexpr int kq = (K) >> 2, kc = (K) & 3; \
    float akc = (kc == 0) ? a0 : (kc == 1) ? a1 : (kc == 2) ? a2 : a3; \
    union { float f; int i; } ua_, uf_, up_; \
    ua_.f = akc; \
    up_.i = __builtin_amdgcn_readlane(ua_.i, ((K) << 2) | kq); \
    uf_.i = __builtin_amdgcn_mov_dpp(ua_.i, kq * 0x55, 0xf, 0xf, 0); \
    float pv = up_.f; \
    float f  = uf_.f; \
    float q0 = __shfl(a0, ((K) << 2) | gq2); \
    float q1 = __shfl(a1, ((K) << 2) | gq2); \
    float q2 = __shfl(a2, ((K) << 2) | gq2); \
    float q3 = __shfl(a3, ((K) << 2) | gq2); \
    float pinv = 1.0f / pv; \
    bool piv = (gi == (K)); \
    float r0 = q0 * pinv, r1 = q1 * pinv, r2 = q2 * pinv, r3 = q3 * pinv; \
    a0 = piv ? r0 : fmaf(-f, r0, a0); \
    a1 = piv ? r1 : fmaf(-f, r1, a1); \
    a2 = piv ? r2 : fmaf(-f, r2, a2); \
    a3 = piv ? r3 : fmaf(-f, r3, a3); \
    float colv = piv ? pinv : -f * pinv; \
    bool fix = (gq2 == kq); \
    if      (kc == 0) a0 = fix ? colv : a0; \
    else if (kc == 1) a1 = fix ? colv : a1; \
    else if (kc == 2) a2 = fix ? colv : a2; \
    else              a3 = fix ? colv : a3; \
}

// One block per batch (2048 blocks, 256 thr, occupancy 6). R11 schedule +
// DPP GJ + DPP reductions + register t4c + no strided diag gathers.
// Thread t owns cur row (ku,iu)=G[b,ku,iu,:].
// scalar[b] = <Aprev-Acur,Minv> - sum_i dT[i]*R[i] + sum_m T[m]*Q[m] - <term4,Minv>
__global__ __launch_bounds__(256, 6)
void curvature_kernel(const float* __restrict__ metric,
                      const float* __restrict__ gamma,
                      float* __restrict__ out)
{
    const int bid = blockIdx.x;
    const int b = ((bid & 7) << 8) | (bid >> 3);   // XCD swizzle: b, b-1 share an L2
    const int t = threadIdx.x;
    const int wv = t >> 6, lane = t & 63;
    const int ku = t >> 4, iu = t & 15;
    const int r16 = lane & 15, hi = lane >> 4;     // r16 == iu, hi == ku&3
    const int gjw = b & 3;                          // GJ wave id: spread across SIMDs

    __shared__ alignas(16) unsigned short XA[16][264];  // XA[b][a*16+c] = G[a,b,c]
    __shared__ alignas(16) float MINV[16][20];
    __shared__ alignas(16) float TT[16][20];             // TT[m][k] = G[k,m,k]
    __shared__ float red[4];

    const float* Gc = gamma + ((size_t)b << 12);
    const float* Gp = gamma + ((size_t)((b + NB - 1) & (NB - 1)) << 12);
    const float4* gc4 = (const float4*)(Gc + (t << 4));
    const float4* gp4 = (const float4*)(Gp + (t << 4));
    const bool isGJ = (wv == gjw);

    // ---- cur-tile loads (16 regs) + metric (GJ wave) ----
    float4 g0 = gc4[0], g1 = gc4[1], g2 = gc4[2], g3 = gc4[3];
    float4 mrow = {0.f, 0.f, 0.f, 0.f};
    if (isGJ) mrow = ((const float4*)(metric + ((size_t)b << 8)))[lane];

    // gku = cur[ku,iu,ku] via cndmask chain (no strided gather)
    float gku;
    {
        float4 gq[4] = {g0, g1, g2, g3};
        gku = g0.x;
        #pragma unroll
        for (int k = 1; k < 16; ++k) {
            float v = qget(gq[k >> 2], k & 3);
            gku = (ku == k) ? v : gku;
        }
    }

    // ---- GJ wave: Gauss-Jordan inverse (SPD, no pivoting), BEFORE barA ----
    if (isGJ) {
        const int gi = lane >> 2, gq2 = lane & 3;
        float a0 = mrow.x, a1 = mrow.y, a2 = mrow.z, a3 = mrow.w;
        GJ_STEP(0)  GJ_STEP(1)  GJ_STEP(2)  GJ_STEP(3)
        GJ_STEP(4)  GJ_STEP(5)  GJ_STEP(6)  GJ_STEP(7)
        GJ_STEP(8)  GJ_STEP(9)  GJ_STEP(10) GJ_STEP(11)
        GJ_STEP(12) GJ_STEP(13) GJ_STEP(14) GJ_STEP(15)
        MINV[gi][4*gq2 + 0] = a0;
        MINV[gi][4*gq2 + 1] = a1;
        MINV[gi][4*gq2 + 2] = a2;
        MINV[gi][4*gq2 + 3] = a3;
    }

    // ---- pack cur to bf16, stage XA (contiguous b128) ----
    {
        float4 gq[4] = {g0, g1, g2, g3};
        unsigned yp[8];
        #pragma unroll
        for (int q = 0; q < 8; ++q) {
            union { __hip_bfloat162 h; unsigned u; } cv;
            cv.h = __float22bfloat162_rn(
                make_float2(qget(gq[q >> 1], (q & 1) * 2),
                            qget(gq[q >> 1], (q & 1) * 2 + 1)));
            yp[q] = cv.u;
        }
        uint4* xd = (uint4*)&XA[iu][ku << 4];
        xd[0] = make_uint4(yp[0], yp[1], yp[2], yp[3]);
        xd[1] = make_uint4(yp[4], yp[5], yp[6], yp[7]);
    }
    TT[iu][ku] = gku;
    __syncthreads();   // barA: XA, TT, MINV visible

    // ---- Minv row (broadcast b128 reads) ----
    float4 m0, m1, m2, m3;
    {
        const float4* mv = (const float4*)&MINV[iu][0];
        m0 = mv[0]; m1 = mv[1]; m2 = mv[2]; m3 = mv[3];
    }

    // ---- every wave: 2 K-steps of the 16x16x256 MFMA ----
    // A-frag: contiguous b128. B-frag: u16 gather (proven slot-consistent l).
    f32x4 acc = {0.f, 0.f, 0.f, 0.f};
    #pragma unroll
    for (int s = 0; s < 2; ++s) {
        const int S = 2 * wv + s;
        bf16x8 av = *(const bf16x8*)&XA[r16][(S << 5) + (hi << 3)];
        const int brow = 2 * S + (hi >> 1);
        const int cbase = ((hi & 1) << 7) + r16;
        bf16x8 bv;
        #pragma unroll
        for (int e = 0; e < 8; ++e)
            bv[e] = (short)XA[brow][cbase + (e << 4)];
        acc = __builtin_amdgcn_mfma_f32_16x16x32_bf16(av, bv, acc, 0, 0, 0);
    }

    // ---- stream prev: pd = <prev,mr>; pku via in-loop cndmask (R11 style) ----
    float pd = 0.f, pku = 0.f;
    {
        float4 v0 = gp4[0], v1 = gp4[1], v2 = gp4[2], v3 = gp4[3];
        float4 vq[4] = {v0, v1, v2, v3};
        #pragma unroll
        for (int k = 0; k < 16; ++k) {
            float v = qget(vq[k >> 2], k & 3);
            float m = qget((k < 4) ? m0 : (k < 8) ? m1 : (k < 12) ? m2 : m3, k & 3);
            pd = fmaf(v, m, pd);
            pku = (ku == k) ? v : pku;
        }
    }

    // ---- qd = <cur,mr>, R = sum mr ----
    float qd = 0.f, R = 0.f;
    {
        float4 gq[4] = {g0, g1, g2, g3};
        #pragma unroll
        for (int k = 0; k < 16; ++k) {
            float m = qget((k < 4) ? m0 : (k < 8) ? m1 : (k < 12) ? m2 : m3, k & 3);
            qd = fmaf(qget(gq[k >> 2], k & 3), m, qd);
            R += m;
        }
    }

    // ---- group-16 DPP sums: tsum = T[ku], qsum = sum qd (land at iu==15) ----
    float tsum = TT[ku][iu];       // transpose exchange (1 b32, conflict-free)
    float qsum = qd;
    ROWSUM16(tsum)
    ROWSUM16(qsum)

    float dt = pku - gku;
    // t4c via Minv symmetry: MINV[4hi+q][r16] == mr[4hi+q]  (r16==iu)
    float4 mq = (hi == 0) ? m0 : (hi == 1) ? m1 : (hi == 2) ? m2 : m3;
    float t4c = acc[0] * mq.x + acc[1] * mq.y + acc[2] * mq.z + acc[3] * mq.w;

    float s = pd - dt * R - t4c;
    if (iu == 15) s = fmaf(tsum - 1.0f, qsum, s);  // group term once per 16-group

    // ---- wave sum via DPP (total lands in lane 63) ----
    ROWSUM16(s)
    s += dpp_mov<0x142>(s);   // row_bcast15
    s += dpp_mov<0x143>(s);   // row_bcast31
    if (lane == 63) red[wv] = s;
    __syncthreads();
    if (t == 0) out[b] = (red[0] + red[1]) + (red[2] + red[3]);
}

extern "C" void kernel_launch(void* const* d_in, const int* in_sizes, int n_in,
                              void* d_out, int out_size, void* d_ws, size_t ws_size,
                              hipStream_t stream) {
    const float* metric = (const float*)d_in[0];   // (2048, 16, 16) f32
    const float* gamma  = (const float*)d_in[1];   // (2048, 16, 16, 16) f32
    float* out = (float*)d_out;                    // (2048,) f32
    curvature_kernel<<<NB, 256, 0, stream>>>(metric, gamma, out);
}

// Round 18
// 12.356 us; speedup vs baseline: 1.1011x; 1.0082x over previous
//
#include <hip/hip_runtime.h>
#include <hip/hip_bf16.h>

#define NB 2048

typedef __attribute__((ext_vector_type(8))) short bf16x8;
typedef __attribute__((ext_vector_type(4))) float f32x4;

__device__ __forceinline__ float qget(const float4& q, int c) {
    return c == 0 ? q.x : c == 1 ? q.y : c == 2 ? q.z : q.w;
}

// DPP move (bound_ctrl=1). VALU pipe — no LDS.
template<int CTRL>
__device__ __forceinline__ float dpp_mov(float x) {
    union { float f; int i; } u; u.f = x;
    u.i = __builtin_amdgcn_mov_dpp(u.i, CTRL, 0xf, 0xf, true);
    return u.f;
}
// sum over each row-of-16; result lands in lane 15 of each row
#define ROWSUM16(x) { x += dpp_mov<0x111>(x); x += dpp_mov<0x112>(x); \
                      x += dpp_mov<0x114>(x); x += dpp_mov<0x118>(x); }

// One Gauss-Jordan step (K literal). pv: readlane; f: DPP quad bcast; q: bpermute.
#define GJ_STEP(K) { \
    constexpr int kq = (K) >> 2, kc = (K) & 3; \
    float akc = (kc == 0) ? a0 : (kc == 1) ? a1 : (kc == 2) ? a2 : a3; \
    union { float f; int i; } ua_, uf_, up_; \
    ua_.f = akc; \
    up_.i = __builtin_amdgcn_readlane(ua_.i, ((K) << 2) | kq); \
    uf_.i = __builtin_amdgcn_mov_dpp(ua_.i, kq * 0x55, 0xf, 0xf, 0); \
    float pv = up_.f; \
    float f  = uf_.f; \
    float q0 = __shfl(a0, ((K) << 2) | gq2); \
    float q1 = __shfl(a1, ((K) << 2) | gq2); \
    float q2 = __shfl(a2, ((K) << 2) | gq2); \
    float q3 = __shfl(a3, ((K) << 2) | gq2); \
    float pinv = 1.0f / pv; \
    bool piv = (gi == (K)); \
    float r0 = q0 * pinv, r1 = q1 * pinv, r2 = q2 * pinv, r3 = q3 * pinv; \
    a0 = piv ? r0 : fmaf(-f, r0, a0); \
    a1 = piv ? r1 : fmaf(-f, r1, a1); \
    a2 = piv ? r2 : fmaf(-f, r2, a2); \
    a3 = piv ? r3 : fmaf(-f, r3, a3); \
    float colv = piv ? pinv : -f * pinv; \
    bool fix = (gq2 == kq); \
    if      (kc == 0) a0 = fix ? colv : a0; \
    else if (kc == 1) a1 = fix ? colv : a1; \
    else if (kc == 2) a2 = fix ? colv : a2; \
    else              a3 = fix ? colv : a3; \
}

// One block per batch (2048 blocks, 256 thr), OCCUPANCY 8 (32 waves/CU; whole
// problem co-resident). R17 body with qd hoisted before MFMA so the two f32
// tiles are never register-live simultaneously (peak ~55 VGPR < 64 cap).
// Thread t owns cur row (ku,iu)=G[b,ku,iu,:].
// scalar[b] = <Aprev-Acur,Minv> - sum_i dT[i]*R[i] + sum_m T[m]*Q[m] - <term4,Minv>
__global__ __launch_bounds__(256, 8)
void curvature_kernel(const float* __restrict__ metric,
                      const float* __restrict__ gamma,
                      float* __restrict__ out)
{
    const int bid = blockIdx.x;
    const int b = ((bid & 7) << 8) | (bid >> 3);   // XCD swizzle: b, b-1 share an L2
    const int t = threadIdx.x;
    const int wv = t >> 6, lane = t & 63;
    const int ku = t >> 4, iu = t & 15;
    const int r16 = lane & 15, hi = lane >> 4;     // r16 == iu, hi == ku&3
    const int gjw = b & 3;                          // GJ wave id: spread across SIMDs

    __shared__ alignas(16) unsigned short XA[16][264];  // XA[b][a*16+c] = G[a,b,c]
    __shared__ alignas(16) float MINV[16][20];
    __shared__ alignas(16) float TT[16][20];             // TT[m][k] = G[k,m,k]
    __shared__ float red[4];

    const float* Gc = gamma + ((size_t)b << 12);
    const float* Gp = gamma + ((size_t)((b + NB - 1) & (NB - 1)) << 12);
    const float4* gc4 = (const float4*)(Gc + (t << 4));
    const float4* gp4 = (const float4*)(Gp + (t << 4));
    const bool isGJ = (wv == gjw);

    // ---- cur-tile loads (16 regs) + metric (GJ wave) ----
    float4 g0 = gc4[0], g1 = gc4[1], g2 = gc4[2], g3 = gc4[3];
    float4 mrow = {0.f, 0.f, 0.f, 0.f};
    if (isGJ) mrow = ((const float4*)(metric + ((size_t)b << 8)))[lane];

    // gku = cur[ku,iu,ku] via cndmask chain (no strided gather)
    float gku;
    {
        float4 gq[4] = {g0, g1, g2, g3};
        gku = g0.x;
        #pragma unroll
        for (int k = 1; k < 16; ++k) {
            float v = qget(gq[k >> 2], k & 3);
            gku = (ku == k) ? v : gku;
        }
    }

    // ---- GJ wave: Gauss-Jordan inverse (SPD, no pivoting), BEFORE barA ----
    if (isGJ) {
        const int gi = lane >> 2, gq2 = lane & 3;
        float a0 = mrow.x, a1 = mrow.y, a2 = mrow.z, a3 = mrow.w;
        GJ_STEP(0)  GJ_STEP(1)  GJ_STEP(2)  GJ_STEP(3)
        GJ_STEP(4)  GJ_STEP(5)  GJ_STEP(6)  GJ_STEP(7)
        GJ_STEP(8)  GJ_STEP(9)  GJ_STEP(10) GJ_STEP(11)
        GJ_STEP(12) GJ_STEP(13) GJ_STEP(14) GJ_STEP(15)
        MINV[gi][4*gq2 + 0] = a0;
        MINV[gi][4*gq2 + 1] = a1;
        MINV[gi][4*gq2 + 2] = a2;
        MINV[gi][4*gq2 + 3] = a3;
    }

    // ---- pack cur to bf16, stage XA (contiguous b128) ----
    {
        float4 gq[4] = {g0, g1, g2, g3};
        unsigned yp[8];
        #pragma unroll
        for (int q = 0; q < 8; ++q) {
            union { __hip_bfloat162 h; unsigned u; } cv;
            cv.h = __float22bfloat162_rn(
                make_float2(qget(gq[q >> 1], (q & 1) * 2),
                            qget(gq[q >> 1], (q & 1) * 2 + 1)));
            yp[q] = cv.u;
        }
        uint4* xd = (uint4*)&XA[iu][ku << 4];
        xd[0] = make_uint4(yp[0], yp[1], yp[2], yp[3]);
        xd[1] = make_uint4(yp[4], yp[5], yp[6], yp[7]);
    }
    TT[iu][ku] = gku;
    __syncthreads();   // barA: XA, TT, MINV visible

    // ---- Minv row (broadcast b128 reads) ----
    float4 m0, m1, m2, m3;
    {
        const float4* mv = (const float4*)&MINV[iu][0];
        m0 = mv[0]; m1 = mv[1]; m2 = mv[2]; m3 = mv[3];
    }

    // ---- qd = <cur,mr>, R = sum mr FIRST: g0..g3 die before prev arrives ----
    float qd = 0.f, R = 0.f;
    {
        float4 gq[4] = {g0, g1, g2, g3};
        #pragma unroll
        for (int k = 0; k < 16; ++k) {
            float m = qget((k < 4) ? m0 : (k < 8) ? m1 : (k < 12) ? m2 : m3, k & 3);
            qd = fmaf(qget(gq[k >> 2], k & 3), m, qd);
            R += m;
        }
    }

    // ---- every wave: 2 K-steps of the 16x16x256 MFMA ----
    // A-frag: contiguous b128. B-frag: u16 gather (proven slot-consistent l).
    f32x4 acc = {0.f, 0.f, 0.f, 0.f};
    #pragma unroll
    for (int s = 0; s < 2; ++s) {
        const int S = 2 * wv + s;
        bf16x8 av = *(const bf16x8*)&XA[r16][(S << 5) + (hi << 3)];
        const int brow = 2 * S + (hi >> 1);
        const int cbase = ((hi & 1) << 7) + r16;
        bf16x8 bv;
        #pragma unroll
        for (int e = 0; e < 8; ++e)
            bv[e] = (short)XA[brow][cbase + (e << 4)];
        acc = __builtin_amdgcn_mfma_f32_16x16x32_bf16(av, bv, acc, 0, 0, 0);
    }

    // ---- stream prev: pd = <prev,mr>; pku via in-loop cndmask ----
    float pd = 0.f, pku = 0.f;
    {
        float4 v0 = gp4[0], v1 = gp4[1], v2 = gp4[2], v3 = gp4[3];
        float4 vq[4] = {v0, v1, v2, v3};
        #pragma unroll
        for (int k = 0; k < 16; ++k) {
            float v = qget(vq[k >> 2], k & 3);
            float m = qget((k < 4) ? m0 : (k < 8) ? m1 : (k < 12) ? m2 : m3, k & 3);
            pd = fmaf(v, m, pd);
            pku = (ku == k) ? v : pku;
        }
    }

    // ---- group-16 DPP sums: tsum = T[ku], qsum = sum qd (land at iu==15) ----
    float tsum = TT[ku][iu];       // transpose exchange (1 b32, conflict-free)
    float qsum = qd;
    ROWSUM16(tsum)
    ROWSUM16(qsum)

    float dt = pku - gku;
    // t4c via Minv symmetry: MINV[4hi+q][r16] == mr[4hi+q]  (r16==iu)
    float4 mq = (hi == 0) ? m0 : (hi == 1) ? m1 : (hi == 2) ? m2 : m3;
    float t4c = acc[0] * mq.x + acc[1] * mq.y + acc[2] * mq.z + acc[3] * mq.w;

    float s = pd - dt * R - t4c;
    if (iu == 15) s = fmaf(tsum - 1.0f, qsum, s);  // group term once per 16-group

    // ---- wave sum via DPP (total lands in lane 63) ----
    ROWSUM16(s)
    s += dpp_mov<0x142>(s);   // row_bcast15
    s += dpp_mov<0x143>(s);   // row_bcast31
    if (lane == 63) red[wv] = s;
    __syncthreads();
    if (t == 0) out[b] = (red[0] + red[1]) + (red[2] + red[3]);
}

extern "C" void kernel_launch(void* const* d_in, const int* in_sizes, int n_in,
                              void* d_out, int out_size, void* d_ws, size_t ws_size,
                              hipStream_t stream) {
    const float* metric = (const float*)d_in[0];   // (2048, 16, 16) f32
    const float* gamma  = (const float*)d_in[1];   // (2048, 16, 16, 16) f32
    float* out = (float*)d_out;                    // (2048,) f32
    curvature_kernel<<<NB, 256, 0, stream>>>(metric, gamma, out);
}